// Round 15
// baseline (42.703 us; speedup 1.0000x reference)
//
#include <hip/hip_runtime.h>
#include <hip/hip_fp16.h>
#include <math.h>

#define H 128
#define W 128
#define BATCH 2

typedef short short8 __attribute__((ext_vector_type(8)));
typedef float f32x4 __attribute__((ext_vector_type(4)));
typedef float f32x16 __attribute__((ext_vector_type(16)));

// ws layout (ushort units):
//  XS planes: 2 x padded NHWC bf16 [2][130][130][64] (h, m split of x)
//  wc2 [36 kstep][64 co][16] bf16 (k-major w_conv)
//  wmeta 2 planes [32][576] (k-order s*64+ci; h then m)
//  meta fp32 [2][128][128][32] at META_OFF
#define BPLANE 1081600
#define PLANE  2163200
#define XS_M   PLANE
#define WC_OFF (2 * PLANE)            // 4326400
#define WM_OFF (WC_OFF + 36864)       // 4363264
#define WM_PLANE 18432
#define META_OFF (WM_OFF + 2 * WM_PLANE)

__device__ __forceinline__ unsigned f2bf_u(float f) {   // RNE bf16 in low 16 bits
    union { float f; unsigned u; } v; v.f = f;
    return (v.u + 0x7FFFu + ((v.u >> 16) & 1u)) >> 16;
}
__device__ __forceinline__ float bfbits2f(unsigned lo16) {
    union { unsigned u; float f; } v; v.u = lo16 << 16;
    return v.f;
}
__device__ __forceinline__ float bfs2f(short s) {
    union { unsigned u; float f; } v; v.u = ((unsigned)(unsigned short)s) << 16;
    return v.f;
}
// 2-way bf16 split: v ~= h + m (residual ~2^-17 relative)
__device__ __forceinline__ void split2(float v, unsigned& h, unsigned& m) {
    h = f2bf_u(v);
    float r1 = v - bfbits2f(h);
    m = f2bf_u(r1);
}

// prep: XCD-aligned transpose + weight layouts (R13).
__global__ __launch_bounds__(512) void prep_kernel(
    const float* __restrict__ x, const float* __restrict__ w_p,
    const float* __restrict__ w_m, const float* __restrict__ w_ad,
    const float* __restrict__ w_conv, unsigned short* __restrict__ ws)
{
    const int blk = blockIdx.x, t = threadIdx.x;
    if (blk < 264) {
        // XCD-aligned row enumeration. xcd = blk%8 = (sub, b); q enumerates rows.
        int xcd = blk & 7, q = blk >> 3;
        int sub = xcd & 3, b = xcd >> 2;
        int hrow;
        if (sub == 0)      { if (q > 32) return; hrow = q; }            // 0..32
        else if (sub == 3) { if (q > 32) return; hrow = 97 + q; }       // 97..129
        else               { if (q > 31) return; hrow = sub * 32 + 1 + q; } // 33..96
        size_t rb = ((size_t)b * 16900 + hrow * 130) * 32;   // u32 units
        unsigned* uh = (unsigned*)ws + rb;
        unsigned* um = (unsigned*)(ws + XS_M) + rb;
        if (hrow == 0 || hrow == 129) {
            for (int f = t; f < 4160; f += 512) { uh[f] = 0; um[f] = 0; }
            return;
        }
        __shared__ float s[64 * 129];   // 33 KB
        int h = hrow - 1;
        for (int f = t; f < 64 * 32; f += 512) {             // float4 loads
            int ci = f >> 5, w4 = f & 31;
            *(float4*)&s[ci * 129 + w4 * 4] =
                *(const float4*)&x[((size_t)(b * 64 + ci) * 128 + h) * 128 + w4 * 4];
        }
        __syncthreads();
        for (int f = t; f < 128 * 8; f += 512) {             // uint4 stores
            int w = f >> 3, g = f & 7;
            unsigned hv[4], mv[4];
            #pragma unroll
            for (int p = 0; p < 4; ++p) {
                int cip = g * 4 + p;
                unsigned h0, m0, h1, m1;
                split2(s[(2 * cip) * 129 + w], h0, m0);
                split2(s[(2 * cip + 1) * 129 + w], h1, m1);
                hv[p] = h0 | (h1 << 16);
                mv[p] = m0 | (m1 << 16);
            }
            int o = (w + 1) * 32 + g * 4;
            *(uint4*)&uh[o] = make_uint4(hv[0], hv[1], hv[2], hv[3]);
            *(uint4*)&um[o] = make_uint4(mv[0], mv[1], mv[2], mv[3]);
        }
        if (t < 32)      { uh[t] = 0; um[t] = 0; }
        else if (t < 64) { int o = 129 * 32 + (t - 32); uh[o] = 0; um[o] = 0; }
    } else if (blk < 282) {
        // w_conv -> wc2 k-major: wc2[(kk*64 + co)*16 + j] = bf16(w_conv[co, klin])
        int q = (blk - 264) * 512 + t;           // 0..9215, 4 ushorts each
        int e = q * 4;
        int j = e & 15, co = (e >> 4) & 63, kk = e >> 10;
        int klin = kk * 16 + j;
        int n = klin >> 6, ci = klin & 63;
        const float* src = w_conv + co * 576 + n;
        ushort4 r;
        r.x = (unsigned short)f2bf_u(src[(ci + 0) * 9]);
        r.y = (unsigned short)f2bf_u(src[(ci + 1) * 9]);
        r.z = (unsigned short)f2bf_u(src[(ci + 2) * 9]);
        r.w = (unsigned short)f2bf_u(src[(ci + 3) * 9]);
        *(ushort4*)(ws + WC_OFF + e) = r;
    } else {
        // meta weights: k-order s*64+ci, 2-way split, rows 30/31 zero
        int q = (blk - 282) * 512 + t;           // 0..18431
        int oc = q / 576, k = q % 576;
        int s = k >> 6, ci = k & 63;
        float v = 0.f;
        if (oc < 18)      v = w_p[oc * 576 + ci * 9 + s];
        else if (oc < 21) v = w_ad[(oc - 18) * 576 + ci * 9 + s];
        else if (oc < 30) v = w_m[(oc - 21) * 576 + ci * 9 + s];
        unsigned hh, mm; split2(v, hh, mm);
        ws[WM_OFF + q] = (unsigned short)hh;
        ws[WM_OFF + WM_PLANE + q] = (unsigned short)mm;
    }
}

// meta v3: 512 blocks = (row, px-half-64); weights staged in LDS (73 KB, 2 blk/CU);
// 8 waves = 4 px-tiles(16) x 2 oc-groups(16). Same 3-pass split 16x16x32 MFMA as R13.
__global__ __launch_bounds__(512, 2) void meta_kernel(
    const float* __restrict__ b_p, const unsigned short* __restrict__ wsu,
    float* __restrict__ meta)
{
    __shared__ __align__(16) unsigned short s_w[64 * 584];   // 74752 B
    const int t = threadIdx.x;
    const int d = blockIdx.x;
    const int idx = d >> 3;
    const int l = (d & 7) * 32 + (idx >> 1);   // XCD-banded rows (match prep/deform)
    const int ph = idx & 1;
    const int b = l >> 7, i = l & 127;

    #pragma unroll
    for (int it = 0; it < 9; ++it) {
        int chunk = it * 512 + t;            // 4608 chunks of 8 ushort
        int r = chunk / 72, c8 = chunk % 72;
        *(short8*)(s_w + r * 584 + c8 * 8) =
            *(const short8*)(wsu + WM_OFF + chunk * 8);
    }
    __syncthreads();

    const int wv = t >> 6, lane = t & 63, lr = lane & 15, lg = lane >> 4;
    const int pt = wv & 3, og = wv >> 2;
    const int px = ph * 64 + pt * 16 + lr;
    const unsigned short* xsb = wsu + (size_t)b * BPLANE;

    f32x4 aA = {0,0,0,0}, aB = {0,0,0,0};
    #pragma unroll
    for (int kk = 0; kk < 18; ++kk) {
        const int s = kk >> 1;
        const unsigned short* bp = xsb + ((i + s / 3) * 130 + (px + s % 3)) * 64
                                   + ((kk & 1) << 5) + lg * 8;
        short8 bh = *(const short8*)(bp);
        short8 bm = *(const short8*)(bp + XS_M);
        const unsigned short* w0 = s_w + (og * 16 + lr) * 584 + kk * 32 + lg * 8;
        short8 ah = *(const short8*)(w0);
        short8 am = *(const short8*)(w0 + 32 * 584);
        aA = __builtin_amdgcn_mfma_f32_16x16x32_bf16(ah, bh, aA, 0, 0, 0);
        aB = __builtin_amdgcn_mfma_f32_16x16x32_bf16(ah, bm, aB, 0, 0, 0);
        aA = __builtin_amdgcn_mfma_f32_16x16x32_bf16(am, bh, aA, 0, 0, 0);
    }

    float* mb = meta + (((size_t)b * 128 + i) * 128 + px) * 32;
    f32x4 o1;
    #pragma unroll
    for (int r = 0; r < 4; ++r) {
        int oc = og * 16 + lg * 4 + r;
        float v = aA[r] + aB[r];
        if (oc < 18)      v += b_p[oc];
        else if (oc < 21) v = 1.f - 1.f / (1.f + expf(-v));
        else              v = 1.f / (1.f + expf(-v));
        o1[r] = v;
    }
    *(f32x4*)(mb + og * 16 + lg * 4) = o1;
}

// deform_kernel: unchanged from R10/R13 (32 px/block, 8 waves = 2 co-halves x 4
// K-quarters, 32x32x16 MFMA). LDS 40832 B -> 4 blocks/CU.
__global__ __launch_bounds__(512, 8) void deform_kernel(
    const unsigned short* __restrict__ wsu, const float* __restrict__ meta,
    float* __restrict__ out)
{
    __shared__ __align__(16) char smem[40832];
    unsigned short* s_valb = (unsigned short*)smem;       // [32][584] bf16
    __half2* s_gh = (__half2*)(smem + 37376);             // [288][2] half2
    int* s_idxp = (int*)(smem + 39680);                   // [288]

    const int t = threadIdx.x;
    const int d = blockIdx.x;
    const int l = (d & 7) * 128 + (d >> 3);   // XCD-contiguous bands
    const int jb = l & 3, i = (l >> 2) & 127, b = l >> 9;
    const int j0 = jb * 32;

    // phase 2: sampling corners + premultiplied bilinear*modulation weights
    if (t < 288) {
        int pix = t / 9, n = t % 9;
        int ki = n / 3, kj = n % 3;
        const float* mrow = meta + (((size_t)b * 128 + i) * 128 + j0 + pix) * 32;
        float adb  = mrow[18 + kj];
        float offx = mrow[n];
        float offy = mrow[9 + n];
        float msig = mrow[21 + n];
        float pnx = (float)(ki - 1), pny = (float)(kj - 1);
        float pxc = (float)(i + 1)        + pnx + offx + 2.f * adb * pnx;
        float pyc = (float)(j0 + pix + 1) + pny + offy + 2.f * adb * pny;

        float flx = floorf(pxc), fly = floorf(pyc);
        int ix0 = (int)fminf(fmaxf(flx,       0.f), 129.f);
        int ix1 = (int)fminf(fmaxf(flx + 1.f, 0.f), 129.f);
        int iy0 = (int)fminf(fmaxf(fly,       0.f), 129.f);
        int iy1 = (int)fminf(fmaxf(fly + 1.f, 0.f), 129.f);

        float ptx = (pxc < 1.f || pxc > 128.f) ? flx : pxc;
        float pty = (pyc < 1.f || pyc > 128.f) ? fly : pyc;
        ptx = fminf(fmaxf(ptx, 0.f), 129.f);
        pty = fminf(fmaxf(pty, 0.f), 129.f);

        float wxl = 1.f + (float)ix0 - ptx;
        float wxr = 1.f - ((float)ix1 - ptx);
        float wyl = 1.f + (float)iy0 - pty;
        float wyr = 1.f - ((float)iy1 - pty);

        float mm = msig * (adb - 0.5f) * 4.f;

        s_gh[t * 2 + 0] = __floats2half2_rn(wxl * wyl * mm, wxr * wyr * mm);
        s_gh[t * 2 + 1] = __floats2half2_rn(wxl * wyr * mm, wxr * wyl * mm);
        s_idxp[t] = ix0 | (ix1 << 8) | (iy0 << 16) | (iy1 << 24);
    }
    __syncthreads();

    // phase 3: bilinear gathers from padded h-plane -> s_valb[pix][n*64+ci]
    const unsigned short* xsb = wsu + (size_t)b * BPLANE;
    #define GATHER(TASK) do {                                                     \
        int task = (TASK);                                                        \
        int n = task >> 8, pix = (task >> 3) & 31, cig = task & 7;                \
        int pk = s_idxp[pix * 9 + n];                                             \
        int ix0 = pk & 255, ix1 = (pk >> 8) & 255;                                \
        int iy0 = (pk >> 16) & 255, iy1 = (pk >> 24) & 255;                       \
        const unsigned short* base = xsb + cig * 8;                               \
        short8 v00 = *(const short8*)(base + (ix0 * 130 + iy0) * 64);             \
        short8 v11 = *(const short8*)(base + (ix1 * 130 + iy1) * 64);             \
        short8 v01 = *(const short8*)(base + (ix0 * 130 + iy1) * 64);             \
        short8 v10 = *(const short8*)(base + (ix1 * 130 + iy0) * 64);             \
        float2 g01 = __half22float2(s_gh[(pix * 9 + n) * 2 + 0]);                 \
        float2 g23 = __half22float2(s_gh[(pix * 9 + n) * 2 + 1]);                 \
        unsigned po[4];                                                           \
        _Pragma("unroll")                                                         \
        for (int jp = 0; jp < 4; ++jp) {                                          \
            float e0 = g01.x * bfs2f(v00[2 * jp])     + g01.y * bfs2f(v11[2 * jp])\
                     + g23.x * bfs2f(v01[2 * jp])     + g23.y * bfs2f(v10[2 * jp]);\
            float e1 = g01.x * bfs2f(v00[2 * jp + 1]) + g01.y * bfs2f(v11[2 * jp + 1])\
                     + g23.x * bfs2f(v01[2 * jp + 1]) + g23.y * bfs2f(v10[2 * jp + 1]);\
            po[jp] = f2bf_u(e0) | (f2bf_u(e1) << 16);                             \
        }                                                                         \
        *(uint4*)(s_valb + pix * 584 + n * 64 + cig * 8)                          \
            = make_uint4(po[0], po[1], po[2], po[3]);                             \
    } while (0)

    #pragma unroll
    for (int it = 0; it < 4; ++it) GATHER(t + it * 512);
    if (t < 256) GATHER(t + 2048);
    #undef GATHER
    __syncthreads();

    // phase 4: 32x32x16 MFMA, waves = (co-half ch, K-quarter kq); A passes L1 once.
    {
        const int w = t >> 6, lane = t & 63;
        const int ch = w & 1, kq = w >> 1;
        const int colA = lane & 31, hi = lane >> 5;
        const unsigned short* wa = wsu + WC_OFF + ((kq * 9) * 64 + ch * 32 + colA) * 16 + hi * 8;
        const unsigned short* vb = s_valb + colA * 584 + (kq * 9) * 16 + hi * 8;
        f32x16 acc = {0,0,0,0,0,0,0,0,0,0,0,0,0,0,0,0};
        #pragma unroll
        for (int s = 0; s < 9; ++s) {
            short8 a   = *(const short8*)(wa + s * 1024);
            short8 bfr = *(const short8*)(vb + s * 16);
            acc = __builtin_amdgcn_mfma_f32_32x32x16_bf16(a, bfr, acc, 0, 0, 0);
        }
        __syncthreads();                      // all waves done reading valb
        float* sp = (float*)smem;             // s_part [8][16][65] f32 (alias valb)
        #pragma unroll
        for (int r = 0; r < 16; ++r)
            sp[(w * 16 + r) * 65 + lane] = acc[r];
        __syncthreads();
        // reduce 4 K-quarters, decode 32x32 C layout, coalesced store
        int ch2 = t >> 8, e = t & 255;
        int lane2 = e & 63, rq = e >> 6;
        #pragma unroll
        for (int q = 0; q < 4; ++q) {
            int reg = rq * 4 + q;
            float v = sp[((0 + ch2) * 16 + reg) * 65 + lane2]
                    + sp[((2 + ch2) * 16 + reg) * 65 + lane2]
                    + sp[((4 + ch2) * 16 + reg) * 65 + lane2]
                    + sp[((6 + ch2) * 16 + reg) * 65 + lane2];
            int col = lane2 & 31;
            int row = (reg & 3) + 8 * (reg >> 2) + 4 * (lane2 >> 5);
            int co = ch2 * 32 + row;
            out[(((size_t)b * 64 + co) * 128 + i) * 128 + j0 + col] = v;
        }
    }
}

extern "C" void kernel_launch(void* const* d_in, const int* in_sizes, int n_in,
                              void* d_out, int out_size, void* d_ws, size_t ws_size,
                              hipStream_t stream) {
    const float* x      = (const float*)d_in[0];
    const float* w_p    = (const float*)d_in[1];
    const float* b_p    = (const float*)d_in[2];
    const float* w_m    = (const float*)d_in[3];
    const float* w_ad   = (const float*)d_in[4];
    const float* w_conv = (const float*)d_in[5];
    float* outp = (float*)d_out;
    unsigned short* ws = (unsigned short*)d_ws;
    float* meta_f = (float*)(ws + META_OFF);

    prep_kernel<<<318, 512, 0, stream>>>(x, w_p, w_m, w_ad, w_conv, ws);
    meta_kernel<<<512, 512, 0, stream>>>(b_p, ws, meta_f);
    deform_kernel<<<1024, 512, 0, stream>>>(ws, meta_f, outp);
}

// Round 16
// 34.056 us; speedup vs baseline: 1.2539x; 1.2539x over previous
//
#include <hip/hip_runtime.h>
#include <hip/hip_fp16.h>
#include <math.h>

#define H 128
#define W 128
#define BATCH 2

typedef short short8 __attribute__((ext_vector_type(8)));
typedef float f32x4 __attribute__((ext_vector_type(4)));
typedef float f32x16 __attribute__((ext_vector_type(16)));

// ws layout (ushort units):
//  XS planes: 2 x padded NHWC bf16 [2][130][130][64] (h, m split of x)
//  wc2 [36 kstep][64 co][16] bf16 (k-major w_conv)
//  wmeta 2 planes [32][576] (k-order s*64+ci; h then m)
//  meta fp32 [2][128][128][32] at META_OFF
#define BPLANE 1081600
#define PLANE  2163200
#define XS_M   PLANE
#define WC_OFF (2 * PLANE)            // 4326400
#define WM_OFF (WC_OFF + 36864)       // 4363264
#define WM_PLANE 18432
#define META_OFF (WM_OFF + 2 * WM_PLANE)

__device__ __forceinline__ unsigned f2bf_u(float f) {   // RNE bf16 in low 16 bits
    union { float f; unsigned u; } v; v.f = f;
    return (v.u + 0x7FFFu + ((v.u >> 16) & 1u)) >> 16;
}
__device__ __forceinline__ float bfbits2f(unsigned lo16) {
    union { unsigned u; float f; } v; v.u = lo16 << 16;
    return v.f;
}
__device__ __forceinline__ float bfs2f(short s) {
    union { unsigned u; float f; } v; v.u = ((unsigned)(unsigned short)s) << 16;
    return v.f;
}
// 2-way bf16 split: v ~= h + m (residual ~2^-17 relative)
__device__ __forceinline__ void split2(float v, unsigned& h, unsigned& m) {
    h = f2bf_u(v);
    float r1 = v - bfbits2f(h);
    m = f2bf_u(r1);
}

// prep v3: transpose in HALF-ROWS (528 blocks -> 2 blocks/CU) with the same
// XCD-aligned banding and vectorized loads/stores. Weight branches unchanged.
__global__ __launch_bounds__(512) void prep_kernel(
    const float* __restrict__ x, const float* __restrict__ w_p,
    const float* __restrict__ w_m, const float* __restrict__ w_ad,
    const float* __restrict__ w_conv, unsigned short* __restrict__ ws)
{
    const int blk = blockIdx.x, t = threadIdx.x;
    if (blk < 528) {
        // xcd = blk%8 keeps the R13 banding; rest = (chalf, q) enumerates half-rows.
        int xcd = blk & 7, rest = blk >> 3;      // rest 0..65
        int chalf = rest & 1, q = rest >> 1;     // q 0..32
        int sub = xcd & 3, b = xcd >> 2;
        int hrow;
        if (sub == 0)      { if (q > 32) return; hrow = q; }                 // 0..32
        else if (sub == 3) { if (q > 32) return; hrow = 97 + q; }            // 97..129
        else               { if (q > 31) return; hrow = sub * 32 + 1 + q; }  // 33..96
        size_t rb = ((size_t)b * 16900 + hrow * 130) * 32;   // u32 units
        unsigned* uh = (unsigned*)ws + rb;
        unsigned* um = (unsigned*)(ws + XS_M) + rb;
        if (hrow == 0 || hrow == 129) {
            for (int f = t + chalf * 2080; f < 2080 + chalf * 2080; f += 512) {
                uh[f] = 0; um[f] = 0;
            }
            return;
        }
        __shared__ float s[64 * 65];   // 16.6 KB
        int h = hrow - 1;
        for (int f = t; f < 64 * 16; f += 512) {             // float4 loads
            int ci = f >> 4, w4 = f & 15;
            *(float4*)&s[ci * 65 + w4 * 4] =
                *(const float4*)&x[((size_t)(b * 64 + ci) * 128 + h) * 128 + chalf * 64 + w4 * 4];
        }
        __syncthreads();
        {
            int f = t;                                        // 512 tasks, 1/thread
            int w = f >> 3, g = f & 7;
            unsigned hv[4], mv[4];
            #pragma unroll
            for (int p = 0; p < 4; ++p) {
                int cip = g * 4 + p;
                unsigned h0, m0, h1, m1;
                split2(s[(2 * cip) * 65 + w], h0, m0);
                split2(s[(2 * cip + 1) * 65 + w], h1, m1);
                hv[p] = h0 | (h1 << 16);
                mv[p] = m0 | (m1 << 16);
            }
            int o = (chalf * 64 + w + 1) * 32 + g * 4;
            *(uint4*)&uh[o] = make_uint4(hv[0], hv[1], hv[2], hv[3]);
            *(uint4*)&um[o] = make_uint4(mv[0], mv[1], mv[2], mv[3]);
        }
        if (chalf == 0) { if (t < 32) { uh[t] = 0; um[t] = 0; } }
        else           { if (t < 32) { int o = 129 * 32 + t; uh[o] = 0; um[o] = 0; } }
    } else if (blk < 546) {
        // w_conv -> wc2 k-major: wc2[(kk*64 + co)*16 + j] = bf16(w_conv[co, klin])
        int q = (blk - 528) * 512 + t;           // 0..9215, 4 ushorts each
        int e = q * 4;
        int j = e & 15, co = (e >> 4) & 63, kk = e >> 10;
        int klin = kk * 16 + j;
        int n = klin >> 6, ci = klin & 63;
        const float* src = w_conv + co * 576 + n;
        ushort4 r;
        r.x = (unsigned short)f2bf_u(src[(ci + 0) * 9]);
        r.y = (unsigned short)f2bf_u(src[(ci + 1) * 9]);
        r.z = (unsigned short)f2bf_u(src[(ci + 2) * 9]);
        r.w = (unsigned short)f2bf_u(src[(ci + 3) * 9]);
        *(ushort4*)(ws + WC_OFF + e) = r;
    } else {
        // meta weights: k-order s*64+ci, 2-way split, rows 30/31 zero
        int q = (blk - 546) * 512 + t;           // 0..18431
        int oc = q / 576, k = q % 576;
        int s = k >> 6, ci = k & 63;
        float v = 0.f;
        if (oc < 18)      v = w_p[oc * 576 + ci * 9 + s];
        else if (oc < 21) v = w_ad[(oc - 18) * 576 + ci * 9 + s];
        else if (oc < 30) v = w_m[(oc - 21) * 576 + ci * 9 + s];
        unsigned hh, mm; split2(v, hh, mm);
        ws[WM_OFF + q] = (unsigned short)hh;
        ws[WM_OFF + WM_PLANE + q] = (unsigned short)mm;
    }
}

// meta v1 (R13-proven) + kk=0,1 B-loads hoisted above the stage barrier.
__global__ __launch_bounds__(512, 2) void meta_kernel(
    const float* __restrict__ b_p, const unsigned short* __restrict__ wsu,
    float* __restrict__ meta)
{
    __shared__ __align__(16) unsigned short s_w[64 * 584];   // 74752 B
    const int t = threadIdx.x;
    const int d = blockIdx.x;
    const int l = (d & 7) * 32 + (d >> 3);   // XCD-contiguous rows
    const int b = l >> 7, i = l & 127;

    const int wv = t >> 6, lane = t & 63, lr = lane & 15, lg = lane >> 4;
    const int px = wv * 16 + lr;
    const unsigned short* xsb = wsu + (size_t)b * BPLANE;

    // Hoisted: B fragments for kk=0,1 (s=0) — independent of LDS; their latency
    // overlaps the stage drain + barrier.
    const unsigned short* bp_pre = xsb + (i * 130 + px) * 64 + lg * 8;
    short8 pre_bh0 = *(const short8*)(bp_pre);
    short8 pre_bm0 = *(const short8*)(bp_pre + XS_M);
    short8 pre_bh1 = *(const short8*)(bp_pre + 32);
    short8 pre_bm1 = *(const short8*)(bp_pre + 32 + XS_M);

    #pragma unroll
    for (int it = 0; it < 9; ++it) {
        int chunk = it * 512 + t;            // 4608 chunks of 8 ushort
        int r = chunk / 72, c8 = chunk % 72;
        *(short8*)(s_w + r * 584 + c8 * 8) =
            *(const short8*)(wsu + WM_OFF + chunk * 8);
    }
    __syncthreads();

    f32x4 aA0 = {0,0,0,0}, aB0 = {0,0,0,0}, aA1 = {0,0,0,0}, aB1 = {0,0,0,0};
    #pragma unroll
    for (int kk = 0; kk < 18; ++kk) {
        const int s = kk >> 1;
        short8 bh, bm;
        if (kk == 0)      { bh = pre_bh0; bm = pre_bm0; }
        else if (kk == 1) { bh = pre_bh1; bm = pre_bm1; }
        else {
            const unsigned short* bp = xsb + ((i + s / 3) * 130 + (px + s % 3)) * 64
                                       + ((kk & 1) << 5) + lg * 8;
            bh = *(const short8*)(bp);
            bm = *(const short8*)(bp + XS_M);
        }
        const unsigned short* w0 = s_w + lr * 584 + kk * 32 + lg * 8;
        short8 ah0 = *(const short8*)(w0);
        short8 am0 = *(const short8*)(w0 + 32 * 584);
        const unsigned short* w1 = w0 + 16 * 584;
        short8 ah1 = *(const short8*)(w1);
        short8 am1 = *(const short8*)(w1 + 32 * 584);
        aA0 = __builtin_amdgcn_mfma_f32_16x16x32_bf16(ah0, bh, aA0, 0, 0, 0);
        aB0 = __builtin_amdgcn_mfma_f32_16x16x32_bf16(ah0, bm, aB0, 0, 0, 0);
        aA0 = __builtin_amdgcn_mfma_f32_16x16x32_bf16(am0, bh, aA0, 0, 0, 0);
        aA1 = __builtin_amdgcn_mfma_f32_16x16x32_bf16(ah1, bh, aA1, 0, 0, 0);
        aB1 = __builtin_amdgcn_mfma_f32_16x16x32_bf16(ah1, bm, aB1, 0, 0, 0);
        aA1 = __builtin_amdgcn_mfma_f32_16x16x32_bf16(am1, bh, aA1, 0, 0, 0);
    }

    float* mb = meta + (((size_t)b * 128 + i) * 128 + px) * 32;
    {
        const float4 bq = *(const float4*)(b_p + lg * 4);
        f32x4 o0;
        o0[0] = aA0[0] + aB0[0] + bq.x;
        o0[1] = aA0[1] + aB0[1] + bq.y;
        o0[2] = aA0[2] + aB0[2] + bq.z;
        o0[3] = aA0[3] + aB0[3] + bq.w;
        *(f32x4*)(mb + lg * 4) = o0;
    }
    {
        f32x4 o1;
        #pragma unroll
        for (int r = 0; r < 4; ++r) {
            int oc = 16 + lg * 4 + r;
            float v = aA1[r] + aB1[r];
            if (oc < 18)      v += b_p[oc];
            else if (oc < 21) v = 1.f - 1.f / (1.f + expf(-v));
            else              v = 1.f / (1.f + expf(-v));
            o1[r] = v;
        }
        *(f32x4*)(mb + 16 + lg * 4) = o1;
    }
}

// deform_kernel: byte-identical to R13 (32 px/block, 8 waves = 2 co-halves x 4
// K-quarters, 32x32x16 MFMA). LDS 40832 B -> 4 blocks/CU.
__global__ __launch_bounds__(512, 8) void deform_kernel(
    const unsigned short* __restrict__ wsu, const float* __restrict__ meta,
    float* __restrict__ out)
{
    __shared__ __align__(16) char smem[40832];
    unsigned short* s_valb = (unsigned short*)smem;       // [32][584] bf16
    __half2* s_gh = (__half2*)(smem + 37376);             // [288][2] half2
    int* s_idxp = (int*)(smem + 39680);                   // [288]

    const int t = threadIdx.x;
    const int d = blockIdx.x;
    const int l = (d & 7) * 128 + (d >> 3);   // XCD-contiguous bands
    const int jb = l & 3, i = (l >> 2) & 127, b = l >> 9;
    const int j0 = jb * 32;

    // phase 2: sampling corners + premultiplied bilinear*modulation weights
    if (t < 288) {
        int pix = t / 9, n = t % 9;
        int ki = n / 3, kj = n % 3;
        const float* mrow = meta + (((size_t)b * 128 + i) * 128 + j0 + pix) * 32;
        float adb  = mrow[18 + kj];
        float offx = mrow[n];
        float offy = mrow[9 + n];
        float msig = mrow[21 + n];
        float pnx = (float)(ki - 1), pny = (float)(kj - 1);
        float pxc = (float)(i + 1)        + pnx + offx + 2.f * adb * pnx;
        float pyc = (float)(j0 + pix + 1) + pny + offy + 2.f * adb * pny;

        float flx = floorf(pxc), fly = floorf(pyc);
        int ix0 = (int)fminf(fmaxf(flx,       0.f), 129.f);
        int ix1 = (int)fminf(fmaxf(flx + 1.f, 0.f), 129.f);
        int iy0 = (int)fminf(fmaxf(fly,       0.f), 129.f);
        int iy1 = (int)fminf(fmaxf(fly + 1.f, 0.f), 129.f);

        float ptx = (pxc < 1.f || pxc > 128.f) ? flx : pxc;
        float pty = (pyc < 1.f || pyc > 128.f) ? fly : pyc;
        ptx = fminf(fmaxf(ptx, 0.f), 129.f);
        pty = fminf(fmaxf(pty, 0.f), 129.f);

        float wxl = 1.f + (float)ix0 - ptx;
        float wxr = 1.f - ((float)ix1 - ptx);
        float wyl = 1.f + (float)iy0 - pty;
        float wyr = 1.f - ((float)iy1 - pty);

        float mm = msig * (adb - 0.5f) * 4.f;

        s_gh[t * 2 + 0] = __floats2half2_rn(wxl * wyl * mm, wxr * wyr * mm);
        s_gh[t * 2 + 1] = __floats2half2_rn(wxl * wyr * mm, wxr * wyl * mm);
        s_idxp[t] = ix0 | (ix1 << 8) | (iy0 << 16) | (iy1 << 24);
    }
    __syncthreads();

    // phase 3: bilinear gathers from padded h-plane -> s_valb[pix][n*64+ci]
    const unsigned short* xsb = wsu + (size_t)b * BPLANE;
    #define GATHER(TASK) do {                                                     \
        int task = (TASK);                                                        \
        int n = task >> 8, pix = (task >> 3) & 31, cig = task & 7;                \
        int pk = s_idxp[pix * 9 + n];                                             \
        int ix0 = pk & 255, ix1 = (pk >> 8) & 255;                                \
        int iy0 = (pk >> 16) & 255, iy1 = (pk >> 24) & 255;                       \
        const unsigned short* base = xsb + cig * 8;                               \
        short8 v00 = *(const short8*)(base + (ix0 * 130 + iy0) * 64);             \
        short8 v11 = *(const short8*)(base + (ix1 * 130 + iy1) * 64);             \
        short8 v01 = *(const short8*)(base + (ix0 * 130 + iy1) * 64);             \
        short8 v10 = *(const short8*)(base + (ix1 * 130 + iy0) * 64);             \
        float2 g01 = __half22float2(s_gh[(pix * 9 + n) * 2 + 0]);                 \
        float2 g23 = __half22float2(s_gh[(pix * 9 + n) * 2 + 1]);                 \
        unsigned po[4];                                                           \
        _Pragma("unroll")                                                         \
        for (int jp = 0; jp < 4; ++jp) {                                          \
            float e0 = g01.x * bfs2f(v00[2 * jp])     + g01.y * bfs2f(v11[2 * jp])\
                     + g23.x * bfs2f(v01[2 * jp])     + g23.y * bfs2f(v10[2 * jp]);\
            float e1 = g01.x * bfs2f(v00[2 * jp + 1]) + g01.y * bfs2f(v11[2 * jp + 1])\
                     + g23.x * bfs2f(v01[2 * jp + 1]) + g23.y * bfs2f(v10[2 * jp + 1]);\
            po[jp] = f2bf_u(e0) | (f2bf_u(e1) << 16);                             \
        }                                                                         \
        *(uint4*)(s_valb + pix * 584 + n * 64 + cig * 8)                          \
            = make_uint4(po[0], po[1], po[2], po[3]);                             \
    } while (0)

    #pragma unroll
    for (int it = 0; it < 4; ++it) GATHER(t + it * 512);
    if (t < 256) GATHER(t + 2048);
    #undef GATHER
    __syncthreads();

    // phase 4: 32x32x16 MFMA, waves = (co-half ch, K-quarter kq); A passes L1 once.
    {
        const int w = t >> 6, lane = t & 63;
        const int ch = w & 1, kq = w >> 1;
        const int colA = lane & 31, hi = lane >> 5;
        const unsigned short* wa = wsu + WC_OFF + ((kq * 9) * 64 + ch * 32 + colA) * 16 + hi * 8;
        const unsigned short* vb = s_valb + colA * 584 + (kq * 9) * 16 + hi * 8;
        f32x16 acc = {0,0,0,0,0,0,0,0,0,0,0,0,0,0,0,0};
        #pragma unroll
        for (int s = 0; s < 9; ++s) {
            short8 a   = *(const short8*)(wa + s * 1024);
            short8 bfr = *(const short8*)(vb + s * 16);
            acc = __builtin_amdgcn_mfma_f32_32x32x16_bf16(a, bfr, acc, 0, 0, 0);
        }
        __syncthreads();                      // all waves done reading valb
        float* sp = (float*)smem;             // s_part [8][16][65] f32 (alias valb)
        #pragma unroll
        for (int r = 0; r < 16; ++r)
            sp[(w * 16 + r) * 65 + lane] = acc[r];
        __syncthreads();
        // reduce 4 K-quarters, decode 32x32 C layout, coalesced store
        int ch2 = t >> 8, e = t & 255;
        int lane2 = e & 63, rq = e >> 6;
        #pragma unroll
        for (int q = 0; q < 4; ++q) {
            int reg = rq * 4 + q;
            float v = sp[((0 + ch2) * 16 + reg) * 65 + lane2]
                    + sp[((2 + ch2) * 16 + reg) * 65 + lane2]
                    + sp[((4 + ch2) * 16 + reg) * 65 + lane2]
                    + sp[((6 + ch2) * 16 + reg) * 65 + lane2];
            int col = lane2 & 31;
            int row = (reg & 3) + 8 * (reg >> 2) + 4 * (lane2 >> 5);
            int co = ch2 * 32 + row;
            out[(((size_t)b * 64 + co) * 128 + i) * 128 + j0 + col] = v;
        }
    }
}

extern "C" void kernel_launch(void* const* d_in, const int* in_sizes, int n_in,
                              void* d_out, int out_size, void* d_ws, size_t ws_size,
                              hipStream_t stream) {
    const float* x      = (const float*)d_in[0];
    const float* w_p    = (const float*)d_in[1];
    const float* b_p    = (const float*)d_in[2];
    const float* w_m    = (const float*)d_in[3];
    const float* w_ad   = (const float*)d_in[4];
    const float* w_conv = (const float*)d_in[5];
    float* outp = (float*)d_out;
    unsigned short* ws = (unsigned short*)d_ws;
    float* meta_f = (float*)(ws + META_OFF);

    prep_kernel<<<582, 512, 0, stream>>>(x, w_p, w_m, w_ad, w_conv, ws);
    meta_kernel<<<256, 512, 0, stream>>>(b_p, ws, meta_f);
    deform_kernel<<<1024, 512, 0, stream>>>(ws, meta_f, outp);
}